// Round 9
// baseline (231.069 us; speedup 1.0000x reference)
//
#include <hip/hip_runtime.h>
#include <hip/hip_bf16.h>
#include <cstdint>

#define DIN 16
#define HD  128
#define RNG 1024    // nodes per bin
#define LB  10      // log2(RNG)
#define MAXB 128    // max bins (N <= 131072)
#define PB  256     // partition/hist blocks

static __device__ __forceinline__ void fma4(float4& a, float s, const float4 v) {
    a.x = fmaf(s, v.x, a.x);
    a.y = fmaf(s, v.y, a.y);
    a.z = fmaf(s, v.z, a.z);
    a.w = fmaf(s, v.w, a.w);
}

// ---------------- dispatch 1: blocks [0,PB) bin-histogram; block PB folds weights -------
__global__ __launch_bounds__(256) void k_histfold(const int* __restrict__ dst,
                                                  int* __restrict__ hist,
                                                  int E, int R, int CHK,
                                                  const float* __restrict__ W1,
                                                  const float* __restrict__ b1,
                                                  const float* __restrict__ W2,
                                                  const float* __restrict__ b2,
                                                  const float* __restrict__ Wout,
                                                  const float* __restrict__ bout,
                                                  float* __restrict__ Wcp,
                                                  float* __restrict__ cbuf) {
    int tid = threadIdx.x;
    if (blockIdx.x < PB) {
        __shared__ int h[MAXB];
        for (int i = tid; i < R; i += 256) h[i] = 0;
        __syncthreads();
        int e0 = blockIdx.x * CHK;
        int e1 = e0 + CHK; if (e1 > E) e1 = E;
        for (int e = e0 + tid; e < e1; e += 256) atomicAdd(&h[dst[e] >> LB], 1);
        __syncthreads();
        for (int i = tid; i < R; i += 256) hist[i * PB + blockIdx.x] = h[i];
        return;
    }
    // weight folding: Wc = W1@W2@Wout, c1 = (W2@Wout)^T b1, b'' = Wout^T b2 + bout
    __shared__ float sT[HD * 3];
    for (int idx = tid; idx < HD * 3; idx += 256) {
        int k = idx / 3, o = idx - 3 * k;
        float s = 0.f;
        for (int j = 0; j < HD; j++) s = fmaf(W2[k * HD + j], Wout[j * 3 + o], s);
        sT[idx] = s;
    }
    if (tid < 3) {
        float s = bout[tid];
        for (int j = 0; j < HD; j++) s = fmaf(b2[j], Wout[j * 3 + tid], s);
        cbuf[3 + tid] = s;
    }
    __syncthreads();
    if (tid < 3) {
        float s = 0.f;
        for (int j = 0; j < HD; j++) s = fmaf(b1[j], sT[j * 3 + tid], s);
        cbuf[tid] = s;
    }
    for (int idx = tid; idx < HD * 3; idx += 256) {
        int k = idx / 3, o = idx - 3 * k;
        float s = 0.f;
        for (int j = 0; j < HD; j++) s = fmaf(W1[k * HD + j], sT[j * 3 + o], s);
        Wcp[k * 4 + o] = s;
    }
    for (int idx = tid; idx < HD; idx += 256) Wcp[idx * 4 + 3] = 0.f;
}

// ---------------- dispatch 2: block 0 scans hist; blocks 1.. run input MLP (unscaled Y) --
// Conflict-free LDS layouts: lane stride = 4 words -> 2-way aliasing (free on gfx950).
__global__ __launch_bounds__(1024) void k_scanmlp(int* __restrict__ hist, int nh,
                                                  const float* __restrict__ F,
                                                  const float* __restrict__ Win,
                                                  const float* __restrict__ bin,
                                                  const float4* __restrict__ Wcp,
                                                  float4* __restrict__ Y, int N) {
    int tid = threadIdx.x;
    if (blockIdx.x == 0) {
        __shared__ int sd[1024];
        int CH = (nh + 1023) / 1024;
        int c0 = tid * CH;
        int c1 = c0 + CH; if (c1 > nh) c1 = nh;
        int sum = 0;
        for (int i = c0; i < c1; i++) sum += hist[i];
        sd[tid] = sum;
        __syncthreads();
        for (int off = 1; off < 1024; off <<= 1) {
            int t = (tid >= off) ? sd[tid - off] : 0;
            __syncthreads();
            sd[tid] += t;
            __syncthreads();
        }
        int base = sd[tid] - sum;
        for (int i = c0; i < c1; i++) { int t = hist[i]; hist[i] = base; base += t; }
        return;
    }
    __shared__ float4 sWinT[DIN * HD / 4];  // [k][c][l] : idx = k*32 + c*16 + l
    __shared__ float4 sWcT[HD];             // [jj][l]   : idx = jj*16 + l
    __shared__ float4 sBin[HD / 4];
    __shared__ float  sF[64 * DIN];         // 4 KB
    if (tid < DIN * HD / 4) {               // 512 float4
        int k = tid >> 5, rem = tid & 31, l = rem >> 1, c = rem & 1;
        sWinT[k * 32 + c * 16 + l] = ((const float4*)Win)[tid];
    } else if (tid < DIN * HD / 4 + HD) {   // 128 float4
        int i = tid - DIN * HD / 4;
        sWcT[(i & 7) * 16 + (i >> 3)] = Wcp[i];
    } else if (tid < DIN * HD / 4 + HD + HD / 4) {
        int i = tid - DIN * HD / 4 - HD;
        sBin[i] = ((const float4*)bin)[i];
    }
    int base = (blockIdx.x - 1) * 64;
    {
        int node = base + (tid >> 4);
        sF[tid] = (node < N) ? F[(size_t)base * DIN + tid] : 0.f;
    }
    __syncthreads();
    int l = tid & 15;        // lane owns hidden features 8l..8l+7
    int g = tid >> 4;
    int node = base + g;
    if (node >= N) return;
    float4 h0 = sBin[l * 2 + 0];
    float4 h1 = sBin[l * 2 + 1];
    #pragma unroll
    for (int k = 0; k < DIN; k++) {
        float f = sF[g * DIN + k];
        fma4(h0, f, sWinT[k * 32 + l]);
        fma4(h1, f, sWinT[k * 32 + 16 + l]);
    }
    h0.x = h0.x > 0.f ? h0.x : 0.01f * h0.x;
    h0.y = h0.y > 0.f ? h0.y : 0.01f * h0.y;
    h0.z = h0.z > 0.f ? h0.z : 0.01f * h0.z;
    h0.w = h0.w > 0.f ? h0.w : 0.01f * h0.w;
    h1.x = h1.x > 0.f ? h1.x : 0.01f * h1.x;
    h1.y = h1.y > 0.f ? h1.y : 0.01f * h1.y;
    h1.z = h1.z > 0.f ? h1.z : 0.01f * h1.z;
    h1.w = h1.w > 0.f ? h1.w : 0.01f * h1.w;
    float hv[8] = {h0.x, h0.y, h0.z, h0.w, h1.x, h1.y, h1.z, h1.w};
    float a0 = 0.f, a1 = 0.f, a2 = 0.f;
    #pragma unroll
    for (int jj = 0; jj < 8; jj++) {
        float4 wc = sWcT[jj * 16 + l];
        a0 = fmaf(hv[jj], wc.x, a0);
        a1 = fmaf(hv[jj], wc.y, a1);
        a2 = fmaf(hv[jj], wc.z, a2);
    }
    #pragma unroll
    for (int off = 8; off > 0; off >>= 1) {
        a0 += __shfl_down(a0, off, 16);
        a1 += __shfl_down(a1, off, 16);
        a2 += __shfl_down(a2, off, 16);
    }
    if (l == 0) Y[node] = make_float4(a0, a1, a2, 1.0f);
}

// ---------------- dispatch 3: deterministic partition (LDS cursors, no global atomics) ---
__global__ __launch_bounds__(256) void k_part(const int* __restrict__ src,
                                              const int* __restrict__ dst,
                                              const int* __restrict__ off,
                                              int2* __restrict__ ebin,
                                              int E, int R, int CHK) {
    __shared__ int cur[MAXB];
    int tid = threadIdx.x;
    int b = blockIdx.x;
    for (int i = tid; i < R; i += 256) cur[i] = off[i * PB + b];
    __syncthreads();
    int e0 = b * CHK;
    int e1 = e0 + CHK; if (e1 > E) e1 = E;
    for (int e = e0 + tid; e < e1; e += 256) {
        int s = src[e], d = dst[e];
        int pos = atomicAdd(&cur[d >> LB], 1);     // LDS atomic
        ebin[pos] = make_int2(s, d & (RNG - 1));
    }
}

// ---------------- dispatch 4: per-bin degree -> dinv, and scale Ys = dinv*Y ----------
__global__ __launch_bounds__(1024) void k_degscale(const int2* __restrict__ ebin,
                                                   const int* __restrict__ off,
                                                   const float4* __restrict__ Y,
                                                   float* __restrict__ dinv,
                                                   float4* __restrict__ Ys,
                                                   int N, int E, int R) {
    __shared__ int c[RNG];
    int tid = threadIdx.x;
    int b = blockIdx.x;
    c[tid] = 0;
    __syncthreads();
    int e0 = off[b * PB];
    int e1 = (b + 1 < R) ? off[(b + 1) * PB] : E;
    for (int e = e0 + tid; e < e1; e += 1024) atomicAdd(&c[ebin[e].y], 1);
    __syncthreads();
    int node = b * RNG + tid;
    if (node < N) {
        float di = rsqrtf((float)c[tid] + 1.0f);
        dinv[node] = di;
        float4 y = Y[node];
        Ys[node] = make_float4(di * y.x, di * y.y, di * y.z, di);  // y.w == 1
    }
}

// ---------------- dispatch 5: bin-exclusive aggregation A: Z1s[n]=di^2*(Ys[n]+sum Ys[s])
__global__ __launch_bounds__(1024) void k_aggA(const int2* __restrict__ ebin,
                                               const int* __restrict__ off,
                                               const float4* __restrict__ Ys,
                                               const float* __restrict__ dinv,
                                               float4* __restrict__ Z1s,
                                               int N, int E, int R) {
    __shared__ float sa[4 * RNG];   // planar, 16 KB
    int tid = threadIdx.x;
    int b = blockIdx.x;
    #pragma unroll
    for (int i = 0; i < 4; i++) sa[i * RNG + tid] = 0.f;
    __syncthreads();
    int e0 = off[b * PB];
    int e1 = (b + 1 < R) ? off[(b + 1) * PB] : E;
    for (int e = e0 + tid; e < e1; e += 1024) {
        int2 ed = ebin[e];
        float4 v = Ys[ed.x];
        atomicAdd(&sa[ed.y], v.x);
        atomicAdd(&sa[RNG + ed.y], v.y);
        atomicAdd(&sa[2 * RNG + ed.y], v.z);
        atomicAdd(&sa[3 * RNG + ed.y], v.w);
    }
    __syncthreads();
    int node = b * RNG + tid;
    if (node < N) {
        float di = dinv[node];
        float d2 = di * di;
        float4 y = Ys[node];
        Z1s[node] = make_float4(d2 * (y.x + sa[tid]),
                                d2 * (y.y + sa[RNG + tid]),
                                d2 * (y.z + sa[2 * RNG + tid]),
                                d2 * (y.w + sa[3 * RNG + tid]));
    }
}

// ---------------- dispatch 6: aggregation B + epilogue ----------------
__global__ __launch_bounds__(1024) void k_aggB(const int2* __restrict__ ebin,
                                               const int* __restrict__ off,
                                               const float4* __restrict__ Z1s,
                                               const float* __restrict__ dinv,
                                               const float* __restrict__ cbuf,
                                               float* __restrict__ out,
                                               int N, int E, int R) {
    __shared__ float sa[4 * RNG];
    int tid = threadIdx.x;
    int b = blockIdx.x;
    #pragma unroll
    for (int i = 0; i < 4; i++) sa[i * RNG + tid] = 0.f;
    __syncthreads();
    int e0 = off[b * PB];
    int e1 = (b + 1 < R) ? off[(b + 1) * PB] : E;
    for (int e = e0 + tid; e < e1; e += 1024) {
        int2 ed = ebin[e];
        float4 v = Z1s[ed.x];
        atomicAdd(&sa[ed.y], v.x);
        atomicAdd(&sa[RNG + ed.y], v.y);
        atomicAdd(&sa[2 * RNG + ed.y], v.z);
        atomicAdd(&sa[3 * RNG + ed.y], v.w);
    }
    __syncthreads();
    int node = b * RNG + tid;
    if (node < N) {
        float di = dinv[node];
        float4 z = Z1s[node];
        float r = z.w / di;                 // (Ahat*1)[n]
        float ax = di * (z.x + sa[tid]);
        float ay = di * (z.y + sa[RNG + tid]);
        float az = di * (z.z + sa[2 * RNG + tid]);
        out[(size_t)node * 3 + 0] = ax + r * cbuf[0] + cbuf[3];
        out[(size_t)node * 3 + 1] = ay + r * cbuf[1] + cbuf[4];
        out[(size_t)node * 3 + 2] = az + r * cbuf[2] + cbuf[5];
    }
}

extern "C" void kernel_launch(void* const* d_in, const int* in_sizes, int n_in,
                              void* d_out, int out_size, void* d_ws, size_t ws_size,
                              hipStream_t stream) {
    const float* feat = (const float*)d_in[0];
    const int*   ei   = (const int*)d_in[1];
    // d_in[2] edge_type: unused (as in reference)
    const float* Win  = (const float*)d_in[3];
    const float* bin  = (const float*)d_in[4];
    const float* W1   = (const float*)d_in[5];
    const float* b1   = (const float*)d_in[6];
    const float* W2   = (const float*)d_in[7];
    const float* b2   = (const float*)d_in[8];
    const float* Wout = (const float*)d_in[9];
    const float* bout = (const float*)d_in[10];
    float* out = (float*)d_out;

    int N = in_sizes[0] / DIN;
    int E = in_sizes[2];
    const int* src = ei;
    const int* dst = ei + E;

    int R = (N + RNG - 1) >> LB;            // 98 for N=100k
    int CHK = (E + PB - 1) / PB;            // edges per hist/part block
    int NH = R * PB;
    int XB = (N + 63) / 64;                 // MLP blocks (64 nodes per 1024-thr block)

    char* p = (char*)d_ws;
    auto alloc = [&](size_t bytes) -> char* {
        char* q = p;
        p += (bytes + 511) & ~(size_t)511;
        return q;
    };
    int*    hist = (int*)alloc((size_t)NH * 4);
    int2*   ebin = (int2*)alloc((size_t)E * 8);
    float4* Y    = (float4*)alloc((size_t)N * 16);
    float4* Ys   = (float4*)alloc((size_t)N * 16);
    float4* Z1s  = (float4*)alloc((size_t)N * 16);
    float*  dinv = (float*)alloc((size_t)N * 4);
    float*  Wcp  = (float*)alloc(HD * 4 * 4);
    float*  cbuf = (float*)alloc(8 * 4);

    k_histfold<<<PB + 1, 256, 0, stream>>>(dst, hist, E, R, CHK,
                                           W1, b1, W2, b2, Wout, bout, Wcp, cbuf);
    k_scanmlp<<<1 + XB, 1024, 0, stream>>>(hist, NH, feat, Win, bin,
                                           (const float4*)Wcp, Y, N);
    k_part<<<PB, 256, 0, stream>>>(src, dst, hist, ebin, E, R, CHK);
    k_degscale<<<R, 1024, 0, stream>>>(ebin, hist, Y, dinv, Ys, N, E, R);
    k_aggA<<<R, 1024, 0, stream>>>(ebin, hist, Ys, dinv, Z1s, N, E, R);
    k_aggB<<<R, 1024, 0, stream>>>(ebin, hist, Z1s, dinv, cbuf, out, N, E, R);
}

// Round 10
// 192.130 us; speedup vs baseline: 1.2027x; 1.2027x over previous
//
#include <hip/hip_runtime.h>
#include <hip/hip_bf16.h>
#include <cstdint>

#define DIN 16
#define HD  128
#define RNG 2048    // nodes per bin
#define LB  11      // log2(RNG)
#define PLN (RNG + 8)  // LDS plane stride: stagger component banks by 8
#define MAXB 64     // max bins (N <= 131072)
#define PB  256     // partition/hist blocks
#define SUB 8       // sub-blocks per bin in agg kernels

static __device__ __forceinline__ void fma4(float4& a, float s, const float4 v) {
    a.x = fmaf(s, v.x, a.x);
    a.y = fmaf(s, v.y, a.y);
    a.z = fmaf(s, v.z, a.z);
    a.w = fmaf(s, v.w, a.w);
}
static __device__ __forceinline__ void add4(float4& a, const float4 v) {
    a.x += v.x; a.y += v.y; a.z += v.z; a.w += v.w;
}

// ---------------- dispatch 1: blocks [0,PB) bin-histogram; block PB folds weights -------
__global__ __launch_bounds__(256) void k_histfold(const int* __restrict__ dst,
                                                  int* __restrict__ hist,
                                                  int E, int R, int CHK,
                                                  const float* __restrict__ W1,
                                                  const float* __restrict__ b1,
                                                  const float* __restrict__ W2,
                                                  const float* __restrict__ b2,
                                                  const float* __restrict__ Wout,
                                                  const float* __restrict__ bout,
                                                  float* __restrict__ Wcp,
                                                  float* __restrict__ cbuf) {
    int tid = threadIdx.x;
    if (blockIdx.x < PB) {
        __shared__ int h[MAXB];
        for (int i = tid; i < R; i += 256) h[i] = 0;
        __syncthreads();
        int e0 = blockIdx.x * CHK;
        int e1 = e0 + CHK; if (e1 > E) e1 = E;
        for (int e = e0 + tid; e < e1; e += 256) atomicAdd(&h[dst[e] >> LB], 1);
        __syncthreads();
        for (int i = tid; i < R; i += 256) hist[i * PB + blockIdx.x] = h[i];
        return;
    }
    // weight folding: Wc = W1@W2@Wout, c1 = (W2@Wout)^T b1, b'' = Wout^T b2 + bout
    __shared__ float sT[HD * 3];
    for (int idx = tid; idx < HD * 3; idx += 256) {
        int k = idx / 3, o = idx - 3 * k;
        float s = 0.f;
        for (int j = 0; j < HD; j++) s = fmaf(W2[k * HD + j], Wout[j * 3 + o], s);
        sT[idx] = s;
    }
    if (tid < 3) {
        float s = bout[tid];
        for (int j = 0; j < HD; j++) s = fmaf(b2[j], Wout[j * 3 + tid], s);
        cbuf[3 + tid] = s;
    }
    __syncthreads();
    if (tid < 3) {
        float s = 0.f;
        for (int j = 0; j < HD; j++) s = fmaf(b1[j], sT[j * 3 + tid], s);
        cbuf[tid] = s;
    }
    for (int idx = tid; idx < HD * 3; idx += 256) {
        int k = idx / 3, o = idx - 3 * k;
        float s = 0.f;
        for (int j = 0; j < HD; j++) s = fmaf(W1[k * HD + j], sT[j * 3 + o], s);
        Wcp[k * 4 + o] = s;
    }
    for (int idx = tid; idx < HD; idx += 256) Wcp[idx * 4 + 3] = 0.f;
}

// ---------------- dispatch 2: block 0 scans hist; blocks 1.. run input MLP (unscaled Y) --
// Conflict-free LDS layouts: lane stride = 4 words -> 2-way aliasing (free on gfx950).
__global__ __launch_bounds__(1024) void k_scanmlp(int* __restrict__ hist, int nh,
                                                  const float* __restrict__ F,
                                                  const float* __restrict__ Win,
                                                  const float* __restrict__ bin,
                                                  const float4* __restrict__ Wcp,
                                                  float4* __restrict__ Y, int N) {
    int tid = threadIdx.x;
    if (blockIdx.x == 0) {
        __shared__ int sd[1024];
        int CH = (nh + 1023) / 1024;
        int c0 = tid * CH;
        int c1 = c0 + CH; if (c1 > nh) c1 = nh;
        int sum = 0;
        for (int i = c0; i < c1; i++) sum += hist[i];
        sd[tid] = sum;
        __syncthreads();
        for (int off = 1; off < 1024; off <<= 1) {
            int t = (tid >= off) ? sd[tid - off] : 0;
            __syncthreads();
            sd[tid] += t;
            __syncthreads();
        }
        int base = sd[tid] - sum;
        for (int i = c0; i < c1; i++) { int t = hist[i]; hist[i] = base; base += t; }
        return;
    }
    __shared__ float4 sWinT[DIN * HD / 4];  // [k][c][l] : idx = k*32 + c*16 + l
    __shared__ float4 sWcT[HD];             // [jj][l]   : idx = jj*16 + l
    __shared__ float4 sBin[HD / 4];
    __shared__ float  sF[64 * DIN];         // 4 KB
    if (tid < DIN * HD / 4) {               // 512 float4
        int k = tid >> 5, rem = tid & 31, l = rem >> 1, c = rem & 1;
        sWinT[k * 32 + c * 16 + l] = ((const float4*)Win)[tid];
    } else if (tid < DIN * HD / 4 + HD) {   // 128 float4
        int i = tid - DIN * HD / 4;
        sWcT[(i & 7) * 16 + (i >> 3)] = Wcp[i];
    } else if (tid < DIN * HD / 4 + HD + HD / 4) {
        int i = tid - DIN * HD / 4 - HD;
        sBin[i] = ((const float4*)bin)[i];
    }
    int base = (blockIdx.x - 1) * 64;
    {
        int node = base + (tid >> 4);
        sF[tid] = (node < N) ? F[(size_t)base * DIN + tid] : 0.f;
    }
    __syncthreads();
    int l = tid & 15;        // lane owns hidden features 8l..8l+7
    int g = tid >> 4;
    int node = base + g;
    if (node >= N) return;
    float4 h0 = sBin[l * 2 + 0];
    float4 h1 = sBin[l * 2 + 1];
    #pragma unroll
    for (int k = 0; k < DIN; k++) {
        float f = sF[g * DIN + k];
        fma4(h0, f, sWinT[k * 32 + l]);
        fma4(h1, f, sWinT[k * 32 + 16 + l]);
    }
    h0.x = h0.x > 0.f ? h0.x : 0.01f * h0.x;
    h0.y = h0.y > 0.f ? h0.y : 0.01f * h0.y;
    h0.z = h0.z > 0.f ? h0.z : 0.01f * h0.z;
    h0.w = h0.w > 0.f ? h0.w : 0.01f * h0.w;
    h1.x = h1.x > 0.f ? h1.x : 0.01f * h1.x;
    h1.y = h1.y > 0.f ? h1.y : 0.01f * h1.y;
    h1.z = h1.z > 0.f ? h1.z : 0.01f * h1.z;
    h1.w = h1.w > 0.f ? h1.w : 0.01f * h1.w;
    float hv[8] = {h0.x, h0.y, h0.z, h0.w, h1.x, h1.y, h1.z, h1.w};
    float a0 = 0.f, a1 = 0.f, a2 = 0.f;
    #pragma unroll
    for (int jj = 0; jj < 8; jj++) {
        float4 wc = sWcT[jj * 16 + l];
        a0 = fmaf(hv[jj], wc.x, a0);
        a1 = fmaf(hv[jj], wc.y, a1);
        a2 = fmaf(hv[jj], wc.z, a2);
    }
    #pragma unroll
    for (int off = 8; off > 0; off >>= 1) {
        a0 += __shfl_down(a0, off, 16);
        a1 += __shfl_down(a1, off, 16);
        a2 += __shfl_down(a2, off, 16);
    }
    if (l == 0) Y[node] = make_float4(a0, a1, a2, 1.0f);
}

// ---------------- dispatch 3: deterministic partition (LDS cursors, no global atomics) ---
__global__ __launch_bounds__(256) void k_part(const int* __restrict__ src,
                                              const int* __restrict__ dst,
                                              const int* __restrict__ off,
                                              int2* __restrict__ ebin,
                                              int E, int R, int CHK) {
    __shared__ int cur[MAXB];
    int tid = threadIdx.x;
    int b = blockIdx.x;
    for (int i = tid; i < R; i += 256) cur[i] = off[i * PB + b];
    __syncthreads();
    int e0 = b * CHK;
    int e1 = e0 + CHK; if (e1 > E) e1 = E;
    for (int e = e0 + tid; e < e1; e += 256) {
        int s = src[e], d = dst[e];
        int pos = atomicAdd(&cur[d >> LB], 1);     // LDS atomic
        ebin[pos] = make_int2(s, d & (RNG - 1));
    }
}

// ---------------- dispatch 4: per-bin degree -> dinv, and scale Ys = dinv*Y ----------
__global__ __launch_bounds__(1024) void k_degscale(const int2* __restrict__ ebin,
                                                   const int* __restrict__ off,
                                                   const float4* __restrict__ Y,
                                                   float* __restrict__ dinv,
                                                   float4* __restrict__ Ys,
                                                   int N, int E, int R) {
    __shared__ int c[RNG];
    int tid = threadIdx.x;
    int b = blockIdx.x;
    c[tid] = 0; c[tid + 1024] = 0;
    __syncthreads();
    int e0 = off[b * PB];
    int e1 = (b + 1 < R) ? off[(b + 1) * PB] : E;
    for (int e = e0 + tid; e < e1; e += 1024) atomicAdd(&c[ebin[e].y], 1);
    __syncthreads();
    #pragma unroll
    for (int k = 0; k < 2; k++) {
        int i = tid + k * 1024;
        int node = b * RNG + i;
        if (node < N) {
            float di = rsqrtf((float)c[i] + 1.0f);
            dinv[node] = di;
            float4 y = Y[node];
            Ys[node] = make_float4(di * y.x, di * y.y, di * y.z, di);  // y.w == 1
        }
    }
}

// ---------------- dispatch 5/7: binned partial aggregation (wide grid: R*SUB blocks) -----
// Staggered planes: component c of node y at sa[c*PLN + y]; banks y, y+8, y+16, y+24.
__global__ __launch_bounds__(512) void k_aggbin(const int2* __restrict__ ebin,
                                                const int* __restrict__ off,
                                                const float4* __restrict__ V,
                                                float4* __restrict__ part,
                                                int E, int R) {
    __shared__ float sa[4 * PLN];   // ~32.1 KB
    int tid = threadIdx.x;
    int b = blockIdx.x / SUB;
    int s = blockIdx.x % SUB;
    for (int i = tid; i < 4 * PLN; i += 512) sa[i] = 0.f;
    __syncthreads();
    int e0 = off[b * PB];
    int e1 = (b + 1 < R) ? off[(b + 1) * PB] : E;
    int len = e1 - e0;
    int lo = e0 + (int)((long long)len * s / SUB);
    int hi = e0 + (int)((long long)len * (s + 1) / SUB);
    for (int e = lo + tid * 2; e < hi; e += 1024) {
        int2 ea = ebin[e];
        bool two = (e + 1 < hi);
        int2 eb = two ? ebin[e + 1] : make_int2(0, 0);
        float4 va = V[ea.x];                       // two independent gathers in flight
        float4 vb = two ? V[eb.x] : make_float4(0.f, 0.f, 0.f, 0.f);
        atomicAdd(&sa[ea.y], va.x);
        atomicAdd(&sa[PLN + ea.y], va.y);
        atomicAdd(&sa[2 * PLN + ea.y], va.z);
        atomicAdd(&sa[3 * PLN + ea.y], va.w);
        if (two) {
            atomicAdd(&sa[eb.y], vb.x);
            atomicAdd(&sa[PLN + eb.y], vb.y);
            atomicAdd(&sa[2 * PLN + eb.y], vb.z);
            atomicAdd(&sa[3 * PLN + eb.y], vb.w);
        }
    }
    __syncthreads();
    float4* pb = part + (size_t)(b * SUB + s) * RNG;
    for (int i = tid; i < RNG; i += 512)
        pb[i] = make_float4(sa[i], sa[PLN + i], sa[2 * PLN + i], sa[3 * PLN + i]);
}

// ---------------- dispatch 6: combine A: Z1s[n] = di^2 * (Ys[n] + sum_s part[s][n]) -----
__global__ __launch_bounds__(256) void k_combA(const float4* __restrict__ Ys,
                                               const float4* __restrict__ part,
                                               const float* __restrict__ dinv,
                                               float4* __restrict__ Z1s, int N) {
    int n = blockIdx.x * blockDim.x + threadIdx.x;
    if (n >= N) return;
    int b = n >> LB, loc = n & (RNG - 1);
    float4 acc = Ys[n];
    const float4* pb = part + (size_t)b * SUB * RNG + loc;
    #pragma unroll
    for (int s = 0; s < SUB; s++) add4(acc, pb[(size_t)s * RNG]);
    float di = dinv[n];
    float d2 = di * di;
    Z1s[n] = make_float4(d2 * acc.x, d2 * acc.y, d2 * acc.z, d2 * acc.w);
}

// ---------------- dispatch 8: combine B + epilogue ----------------
__global__ __launch_bounds__(256) void k_combB(const float4* __restrict__ Z1s,
                                               const float4* __restrict__ part,
                                               const float* __restrict__ dinv,
                                               const float* __restrict__ cbuf,
                                               float* __restrict__ out, int N) {
    int n = blockIdx.x * blockDim.x + threadIdx.x;
    if (n >= N) return;
    int b = n >> LB, loc = n & (RNG - 1);
    float di = dinv[n];
    float4 z = Z1s[n];
    float r = z.w / di;                 // (Ahat*1)[n]
    float4 acc = z;
    const float4* pb = part + (size_t)b * SUB * RNG + loc;
    #pragma unroll
    for (int s = 0; s < SUB; s++) add4(acc, pb[(size_t)s * RNG]);
    out[(size_t)n * 3 + 0] = di * acc.x + r * cbuf[0] + cbuf[3];
    out[(size_t)n * 3 + 1] = di * acc.y + r * cbuf[1] + cbuf[4];
    out[(size_t)n * 3 + 2] = di * acc.z + r * cbuf[2] + cbuf[5];
}

extern "C" void kernel_launch(void* const* d_in, const int* in_sizes, int n_in,
                              void* d_out, int out_size, void* d_ws, size_t ws_size,
                              hipStream_t stream) {
    const float* feat = (const float*)d_in[0];
    const int*   ei   = (const int*)d_in[1];
    // d_in[2] edge_type: unused (as in reference)
    const float* Win  = (const float*)d_in[3];
    const float* bin  = (const float*)d_in[4];
    const float* W1   = (const float*)d_in[5];
    const float* b1   = (const float*)d_in[6];
    const float* W2   = (const float*)d_in[7];
    const float* b2   = (const float*)d_in[8];
    const float* Wout = (const float*)d_in[9];
    const float* bout = (const float*)d_in[10];
    float* out = (float*)d_out;

    int N = in_sizes[0] / DIN;
    int E = in_sizes[2];
    const int* src = ei;
    const int* dst = ei + E;

    int R = (N + RNG - 1) >> LB;            // 49 for N=100k
    int CHK = (E + PB - 1) / PB;            // edges per hist/part block
    int NH = R * PB;
    int XB = (N + 63) / 64;                 // MLP blocks (64 nodes per 1024-thr block)

    char* p = (char*)d_ws;
    auto alloc = [&](size_t bytes) -> char* {
        char* q = p;
        p += (bytes + 511) & ~(size_t)511;
        return q;
    };
    int*    hist = (int*)alloc((size_t)NH * 4);
    int2*   ebin = (int2*)alloc((size_t)E * 8);                  // 6.4 MB
    float4* part = (float4*)alloc((size_t)R * SUB * RNG * 16);   // 12.8 MB (reused A/B)
    float4* Y    = (float4*)alloc((size_t)N * 16);
    float4* Ys   = (float4*)alloc((size_t)N * 16);
    float4* Z1s  = (float4*)alloc((size_t)N * 16);
    float*  dinv = (float*)alloc((size_t)N * 4);
    float*  Wcp  = (float*)alloc(HD * 4 * 4);
    float*  cbuf = (float*)alloc(8 * 4);

    k_histfold<<<PB + 1, 256, 0, stream>>>(dst, hist, E, R, CHK,
                                           W1, b1, W2, b2, Wout, bout, Wcp, cbuf);
    k_scanmlp<<<1 + XB, 1024, 0, stream>>>(hist, NH, feat, Win, bin,
                                           (const float4*)Wcp, Y, N);
    k_part<<<PB, 256, 0, stream>>>(src, dst, hist, ebin, E, R, CHK);
    k_degscale<<<R, 1024, 0, stream>>>(ebin, hist, Y, dinv, Ys, N, E, R);
    k_aggbin<<<R * SUB, 512, 0, stream>>>(ebin, hist, Ys, part, E, R);
    k_combA<<<(N + 255) / 256, 256, 0, stream>>>(Ys, part, dinv, Z1s, N);
    k_aggbin<<<R * SUB, 512, 0, stream>>>(ebin, hist, Z1s, part, E, R);
    k_combB<<<(N + 255) / 256, 256, 0, stream>>>(Z1s, part, dinv, cbuf, out, N);
}

// Round 11
// 160.185 us; speedup vs baseline: 1.4425x; 1.1994x over previous
//
#include <hip/hip_runtime.h>
#include <hip/hip_bf16.h>
#include <cstdint>

#define DIN 16
#define HD  128
#define RNG 2048    // nodes per bin
#define LB  11      // log2(RNG)
#define MAXB 64     // max bins (N <= 131072)
#define PB  256     // partition/hist blocks

static __device__ __forceinline__ void fma4(float4& a, float s, const float4 v) {
    a.x = fmaf(s, v.x, a.x);
    a.y = fmaf(s, v.y, a.y);
    a.z = fmaf(s, v.z, a.z);
    a.w = fmaf(s, v.w, a.w);
}
static __device__ __forceinline__ void add4(float4& a, const float4 v) {
    a.x += v.x; a.y += v.y; a.z += v.z; a.w += v.w;
}

// ---------------- dispatch 1: blocks [0,PB) bin-histogram; block PB folds weights -------
__global__ __launch_bounds__(256) void k_histfold(const int* __restrict__ dst,
                                                  int* __restrict__ hist,
                                                  int E, int R, int CHK,
                                                  const float* __restrict__ W1,
                                                  const float* __restrict__ b1,
                                                  const float* __restrict__ W2,
                                                  const float* __restrict__ b2,
                                                  const float* __restrict__ Wout,
                                                  const float* __restrict__ bout,
                                                  float* __restrict__ Wcp,
                                                  float* __restrict__ cbuf) {
    int tid = threadIdx.x;
    if (blockIdx.x < PB) {
        __shared__ int h[MAXB];
        for (int i = tid; i < R; i += 256) h[i] = 0;
        __syncthreads();
        int e0 = blockIdx.x * CHK;
        int e1 = e0 + CHK; if (e1 > E) e1 = E;
        for (int e = e0 + tid; e < e1; e += 256) atomicAdd(&h[dst[e] >> LB], 1);
        __syncthreads();
        for (int i = tid; i < R; i += 256) hist[i * PB + blockIdx.x] = h[i];
        return;
    }
    // weight folding: Wc = W1@W2@Wout, c1 = (W2@Wout)^T b1, b'' = Wout^T b2 + bout
    __shared__ float sT[HD * 3];
    for (int idx = tid; idx < HD * 3; idx += 256) {
        int k = idx / 3, o = idx - 3 * k;
        float s = 0.f;
        for (int j = 0; j < HD; j++) s = fmaf(W2[k * HD + j], Wout[j * 3 + o], s);
        sT[idx] = s;
    }
    if (tid < 3) {
        float s = bout[tid];
        for (int j = 0; j < HD; j++) s = fmaf(b2[j], Wout[j * 3 + tid], s);
        cbuf[3 + tid] = s;
    }
    __syncthreads();
    if (tid < 3) {
        float s = 0.f;
        for (int j = 0; j < HD; j++) s = fmaf(b1[j], sT[j * 3 + tid], s);
        cbuf[tid] = s;
    }
    for (int idx = tid; idx < HD * 3; idx += 256) {
        int k = idx / 3, o = idx - 3 * k;
        float s = 0.f;
        for (int j = 0; j < HD; j++) s = fmaf(W1[k * HD + j], sT[j * 3 + o], s);
        Wcp[k * 4 + o] = s;
    }
    for (int idx = tid; idx < HD; idx += 256) Wcp[idx * 4 + 3] = 0.f;
}

// ---------------- dispatch 2: block 0 scans hist; blocks 1.. run input MLP (unscaled Y) --
__global__ __launch_bounds__(1024) void k_scanmlp(int* __restrict__ hist, int nh,
                                                  const float* __restrict__ F,
                                                  const float* __restrict__ Win,
                                                  const float* __restrict__ bin,
                                                  const float4* __restrict__ Wcp,
                                                  float4* __restrict__ Y, int N) {
    int tid = threadIdx.x;
    if (blockIdx.x == 0) {
        __shared__ int sd[1024];
        int CH = (nh + 1023) / 1024;
        int c0 = tid * CH;
        int c1 = c0 + CH; if (c1 > nh) c1 = nh;
        int sum = 0;
        for (int i = c0; i < c1; i++) sum += hist[i];
        sd[tid] = sum;
        __syncthreads();
        for (int off = 1; off < 1024; off <<= 1) {
            int t = (tid >= off) ? sd[tid - off] : 0;
            __syncthreads();
            sd[tid] += t;
            __syncthreads();
        }
        int base = sd[tid] - sum;
        for (int i = c0; i < c1; i++) { int t = hist[i]; hist[i] = base; base += t; }
        return;
    }
    __shared__ float4 sWinT[DIN * HD / 4];  // [k][c][l] : idx = k*32 + c*16 + l
    __shared__ float4 sWcT[HD];             // [jj][l]   : idx = jj*16 + l
    __shared__ float4 sBin[HD / 4];
    __shared__ float  sF[64 * DIN];         // 4 KB
    if (tid < DIN * HD / 4) {               // 512 float4
        int k = tid >> 5, rem = tid & 31, l = rem >> 1, c = rem & 1;
        sWinT[k * 32 + c * 16 + l] = ((const float4*)Win)[tid];
    } else if (tid < DIN * HD / 4 + HD) {   // 128 float4
        int i = tid - DIN * HD / 4;
        sWcT[(i & 7) * 16 + (i >> 3)] = Wcp[i];
    } else if (tid < DIN * HD / 4 + HD + HD / 4) {
        int i = tid - DIN * HD / 4 - HD;
        sBin[i] = ((const float4*)bin)[i];
    }
    int base = (blockIdx.x - 1) * 64;
    {
        int node = base + (tid >> 4);
        sF[tid] = (node < N) ? F[(size_t)base * DIN + tid] : 0.f;
    }
    __syncthreads();
    int l = tid & 15;        // lane owns hidden features 8l..8l+7
    int g = tid >> 4;
    int node = base + g;
    if (node >= N) return;
    float4 h0 = sBin[l * 2 + 0];
    float4 h1 = sBin[l * 2 + 1];
    #pragma unroll
    for (int k = 0; k < DIN; k++) {
        float f = sF[g * DIN + k];
        fma4(h0, f, sWinT[k * 32 + l]);
        fma4(h1, f, sWinT[k * 32 + 16 + l]);
    }
    h0.x = h0.x > 0.f ? h0.x : 0.01f * h0.x;
    h0.y = h0.y > 0.f ? h0.y : 0.01f * h0.y;
    h0.z = h0.z > 0.f ? h0.z : 0.01f * h0.z;
    h0.w = h0.w > 0.f ? h0.w : 0.01f * h0.w;
    h1.x = h1.x > 0.f ? h1.x : 0.01f * h1.x;
    h1.y = h1.y > 0.f ? h1.y : 0.01f * h1.y;
    h1.z = h1.z > 0.f ? h1.z : 0.01f * h1.z;
    h1.w = h1.w > 0.f ? h1.w : 0.01f * h1.w;
    float hv[8] = {h0.x, h0.y, h0.z, h0.w, h1.x, h1.y, h1.z, h1.w};
    float a0 = 0.f, a1 = 0.f, a2 = 0.f;
    #pragma unroll
    for (int jj = 0; jj < 8; jj++) {
        float4 wc = sWcT[jj * 16 + l];
        a0 = fmaf(hv[jj], wc.x, a0);
        a1 = fmaf(hv[jj], wc.y, a1);
        a2 = fmaf(hv[jj], wc.z, a2);
    }
    #pragma unroll
    for (int off = 8; off > 0; off >>= 1) {
        a0 += __shfl_down(a0, off, 16);
        a1 += __shfl_down(a1, off, 16);
        a2 += __shfl_down(a2, off, 16);
    }
    if (l == 0) Y[node] = make_float4(a0, a1, a2, 1.0f);
}

// ---------------- dispatch 3: deterministic partition (LDS cursors, no global atomics) ---
__global__ __launch_bounds__(256) void k_part(const int* __restrict__ src,
                                              const int* __restrict__ dst,
                                              const int* __restrict__ off,
                                              int2* __restrict__ ebin,
                                              int E, int R, int CHK) {
    __shared__ int cur[MAXB];
    int tid = threadIdx.x;
    int b = blockIdx.x;
    for (int i = tid; i < R; i += 256) cur[i] = off[i * PB + b];
    __syncthreads();
    int e0 = b * CHK;
    int e1 = e0 + CHK; if (e1 > E) e1 = E;
    for (int e = e0 + tid; e < e1; e += 256) {
        int s = src[e], d = dst[e];
        int pos = atomicAdd(&cur[d >> LB], 1);     // LDS atomic
        ebin[pos] = make_int2(s, d & (RNG - 1));
    }
}

// ---------------- dispatch 4: per-bin counting sort -> CSR (rowptr, ecsr) + dinv + Ys ----
// One block per bin: count (LDS atomics) -> 2048-entry scan -> cursor scatter.
// Bin offsets are globally monotone, so rowptr/ecsr positions are global for free.
__global__ __launch_bounds__(1024) void k_csr(const int2* __restrict__ ebin,
                                              const int* __restrict__ off,
                                              const float4* __restrict__ Y,
                                              int* __restrict__ rowptr,
                                              int* __restrict__ ecsr,
                                              float* __restrict__ dinv,
                                              float4* __restrict__ Ys,
                                              int N, int E, int R) {
    __shared__ int c[RNG];      // counts -> cursors
    __shared__ int sd[1024];
    int tid = threadIdx.x;
    int b = blockIdx.x;
    c[tid] = 0; c[tid + 1024] = 0;
    __syncthreads();
    int e0 = off[b * PB];
    int e1 = (b + 1 < R) ? off[(b + 1) * PB] : E;
    for (int e = e0 + tid; e < e1; e += 1024) atomicAdd(&c[ebin[e].y], 1);
    __syncthreads();
    int v0 = c[2 * tid], v1 = c[2 * tid + 1];
    int ts = v0 + v1;
    sd[tid] = ts;
    __syncthreads();
    for (int o = 1; o < 1024; o <<= 1) {
        int t = (tid >= o) ? sd[tid - o] : 0;
        __syncthreads();
        sd[tid] += t;
        __syncthreads();
    }
    int rp0 = e0 + sd[tid] - ts;            // global CSR start of node b*RNG+2t
    int rp1 = rp0 + v0;
    int n0 = b * RNG + 2 * tid;
    if (n0 <= N) rowptr[n0] = rp0;
    if (n0 + 1 <= N) rowptr[n0 + 1] = rp1;
    if (b == R - 1 && tid == 1023) rowptr[N] = E;   // safe overwrite; exact when N < R*RNG
    if (n0 < N) {
        float di = rsqrtf((float)v0 + 1.0f);
        dinv[n0] = di;
        float4 y = Y[n0];
        Ys[n0] = make_float4(di * y.x, di * y.y, di * y.z, di);   // y.w == 1
    }
    if (n0 + 1 < N) {
        float di = rsqrtf((float)v1 + 1.0f);
        dinv[n0 + 1] = di;
        float4 y = Y[n0 + 1];
        Ys[n0 + 1] = make_float4(di * y.x, di * y.y, di * y.z, di);
    }
    c[2 * tid] = rp0;                        // cursors
    c[2 * tid + 1] = rp1;
    __syncthreads();
    for (int e = e0 + tid; e < e1; e += 1024) {
        int2 ed = ebin[e];
        int pos = atomicAdd(&c[ed.y], 1);    // LDS atomic
        ecsr[pos] = ed.x;
    }
}

// ---------------- dispatch 5: node-parallel agg A: Z1s[n] = di^2*(Ys[n] + sum Ys[s]) -----
__global__ __launch_bounds__(256) void k_aggA(const int* __restrict__ rowptr,
                                              const int* __restrict__ ecsr,
                                              const float4* __restrict__ Ys,
                                              const float* __restrict__ dinv,
                                              float4* __restrict__ Z1s, int N) {
    int n = blockIdx.x * blockDim.x + threadIdx.x;
    if (n >= N) return;
    int beg = rowptr[n], end = rowptr[n + 1];
    float4 acc = Ys[n];
    int j = beg;
    for (; j + 4 <= end; j += 4) {
        int s0 = ecsr[j], s1 = ecsr[j + 1], s2 = ecsr[j + 2], s3 = ecsr[j + 3];
        float4 a = Ys[s0], b = Ys[s1], c = Ys[s2], d = Ys[s3];
        add4(acc, a); add4(acc, b); add4(acc, c); add4(acc, d);
    }
    for (; j < end; j++) add4(acc, Ys[ecsr[j]]);
    float di = dinv[n];
    float d2 = di * di;
    Z1s[n] = make_float4(d2 * acc.x, d2 * acc.y, d2 * acc.z, d2 * acc.w);
}

// ---------------- dispatch 6: node-parallel agg B + epilogue ----------------
__global__ __launch_bounds__(256) void k_aggB(const int* __restrict__ rowptr,
                                              const int* __restrict__ ecsr,
                                              const float4* __restrict__ Z1s,
                                              const float* __restrict__ dinv,
                                              const float* __restrict__ cbuf,
                                              float* __restrict__ out, int N) {
    int n = blockIdx.x * blockDim.x + threadIdx.x;
    if (n >= N) return;
    int beg = rowptr[n], end = rowptr[n + 1];
    float4 acc = Z1s[n];
    float di = dinv[n];
    float r = acc.w / di;                   // (Ahat*1)[n]
    int j = beg;
    for (; j + 4 <= end; j += 4) {
        int s0 = ecsr[j], s1 = ecsr[j + 1], s2 = ecsr[j + 2], s3 = ecsr[j + 3];
        float4 a = Z1s[s0], b = Z1s[s1], c = Z1s[s2], d = Z1s[s3];
        add4(acc, a); add4(acc, b); add4(acc, c); add4(acc, d);
    }
    for (; j < end; j++) add4(acc, Z1s[ecsr[j]]);
    out[(size_t)n * 3 + 0] = di * acc.x + r * cbuf[0] + cbuf[3];
    out[(size_t)n * 3 + 1] = di * acc.y + r * cbuf[1] + cbuf[4];
    out[(size_t)n * 3 + 2] = di * acc.z + r * cbuf[2] + cbuf[5];
}

extern "C" void kernel_launch(void* const* d_in, const int* in_sizes, int n_in,
                              void* d_out, int out_size, void* d_ws, size_t ws_size,
                              hipStream_t stream) {
    const float* feat = (const float*)d_in[0];
    const int*   ei   = (const int*)d_in[1];
    // d_in[2] edge_type: unused (as in reference)
    const float* Win  = (const float*)d_in[3];
    const float* bin  = (const float*)d_in[4];
    const float* W1   = (const float*)d_in[5];
    const float* b1   = (const float*)d_in[6];
    const float* W2   = (const float*)d_in[7];
    const float* b2   = (const float*)d_in[8];
    const float* Wout = (const float*)d_in[9];
    const float* bout = (const float*)d_in[10];
    float* out = (float*)d_out;

    int N = in_sizes[0] / DIN;
    int E = in_sizes[2];
    const int* src = ei;
    const int* dst = ei + E;

    int R = (N + RNG - 1) >> LB;            // 49 for N=100k
    int CHK = (E + PB - 1) / PB;            // edges per hist/part block
    int NH = R * PB;
    int XB = (N + 63) / 64;                 // MLP blocks (64 nodes per 1024-thr block)

    char* p = (char*)d_ws;
    auto alloc = [&](size_t bytes) -> char* {
        char* q = p;
        p += (bytes + 511) & ~(size_t)511;
        return q;
    };
    int*    hist   = (int*)alloc((size_t)NH * 4);
    int2*   ebin   = (int2*)alloc((size_t)E * 8);       // 6.4 MB
    int*    ecsr   = (int*)alloc((size_t)E * 4);        // 3.2 MB
    int*    rowptr = (int*)alloc((size_t)(N + 1) * 4);
    float4* Y      = (float4*)alloc((size_t)N * 16);
    float4* Ys     = (float4*)alloc((size_t)N * 16);
    float4* Z1s    = (float4*)alloc((size_t)N * 16);
    float*  dinv   = (float*)alloc((size_t)N * 4);
    float*  Wcp    = (float*)alloc(HD * 4 * 4);
    float*  cbuf   = (float*)alloc(8 * 4);

    k_histfold<<<PB + 1, 256, 0, stream>>>(dst, hist, E, R, CHK,
                                           W1, b1, W2, b2, Wout, bout, Wcp, cbuf);
    k_scanmlp<<<1 + XB, 1024, 0, stream>>>(hist, NH, feat, Win, bin,
                                           (const float4*)Wcp, Y, N);
    k_part<<<PB, 256, 0, stream>>>(src, dst, hist, ebin, E, R, CHK);
    k_csr<<<R, 1024, 0, stream>>>(ebin, hist, Y, rowptr, ecsr, dinv, Ys, N, E, R);
    k_aggA<<<(N + 255) / 256, 256, 0, stream>>>(rowptr, ecsr, Ys, dinv, Z1s, N);
    k_aggB<<<(N + 255) / 256, 256, 0, stream>>>(rowptr, ecsr, Z1s, dinv, cbuf, out, N);
}